// Round 2
// baseline (3356.829 us; speedup 1.0000x reference)
//
#include <hip/hip_runtime.h>
#include <math.h>

#define SLOPE 0.2291666666666667f

constexpr int N0 = 4110, N1 = 4108, N2 = 4104;

__device__ __forceinline__ float rrelu(float v) { return v >= 0.f ? v : v * SLOPE; }

// Generic k=2 dilated conv, OC=128, IC templated. Wave = 64 t-positions,
// each wave computes 32 output channels (weight indices wave-uniform -> s_loads).
template<int IC, int DIL, int PAD>
__global__ __launch_bounds__(256) void conv_k(const float* __restrict__ in,
    const float* __restrict__ w, const float* __restrict__ bias,
    float* __restrict__ out, int nin, int nout)
{
  constexpr int TILE = 64;
  constexpr int W = TILE + DIL;
  __shared__ float in_s[IC][W];
  const int b = blockIdx.y;
  const int t0 = blockIdx.x * TILE;
  const float* inb = in + (size_t)b * IC * nin;
  for (int e = threadIdx.x; e < IC * W; e += 256) {
    int i = e / W;
    int tt = e - i * W;
    int p = t0 + tt - PAD;
    in_s[i][tt] = (p >= 0 && p < nin) ? inb[(size_t)i * nin + p] : 0.f;
  }
  __syncthreads();
  const int lane = threadIdx.x & 63;
  const int wv = threadIdx.x >> 6;
  const int oc0 = wv * 32;
  float acc[32];
  #pragma unroll
  for (int k = 0; k < 32; ++k) acc[k] = bias[oc0 + k];
  #pragma unroll 4
  for (int i = 0; i < IC; ++i) {
    float v0 = in_s[i][lane];
    float v1 = in_s[i][lane + DIL];
    const float* wp = w + ((size_t)oc0 * IC + i) * 2;
    #pragma unroll
    for (int k = 0; k < 32; ++k) {
      acc[k] = fmaf(wp[(size_t)k * IC * 2], v0, acc[k]);
      acc[k] = fmaf(wp[(size_t)k * IC * 2 + 1], v1, acc[k]);
    }
  }
  const int t = t0 + lane;
  if (t < nout) {
    float* ob = out + (size_t)b * 128 * nout + t;
    #pragma unroll
    for (int k = 0; k < 32; ++k)
      ob[(size_t)(oc0 + k) * nout] = rrelu(acc[k]);
  }
}

// conv3 (128->8, d=8) + rrelu + log-softmax + gumbel-softmax. One thread per (b,t).
// Kept fully fp32: the /0.1 gumbel temperature amplifies any error by 10x.
__global__ __launch_bounds__(256) void gumbel_k(const float* __restrict__ h2,
    const float* __restrict__ w3, const float* __restrict__ b3,
    const float* __restrict__ u, float* __restrict__ genz)
{
  const int idx = blockIdx.x * 256 + threadIdx.x;
  const int b = idx >> 12;
  const int t = idx & 4095;
  const float* hb = h2 + (size_t)b * 128 * N2 + t;
  float acc[8];
  #pragma unroll
  for (int r = 0; r < 8; ++r) acc[r] = b3[r];
  #pragma unroll 4
  for (int i = 0; i < 128; ++i) {
    float v0 = hb[(size_t)i * N2];
    float v1 = hb[(size_t)i * N2 + 8];
    #pragma unroll
    for (int r = 0; r < 8; ++r) {
      acc[r] = fmaf(w3[(r * 128 + i) * 2], v0, acc[r]);
      acc[r] = fmaf(w3[(r * 128 + i) * 2 + 1], v1, acc[r]);
    }
  }
  float m = -1e30f;
  #pragma unroll
  for (int r = 0; r < 8; ++r) { acc[r] = rrelu(acc[r]); m = fmaxf(m, acc[r]); }
  float s = 0.f;
  #pragma unroll
  for (int r = 0; r < 8; ++r) s += __expf(acc[r] - m);
  const float lse = m + __logf(s);
  float y[8];
  float m2 = -1e30f;
  const float* ub = u + ((size_t)b * 4096 + t) * 8;
  #pragma unroll
  for (int r = 0; r < 8; ++r) {
    float g = -__logf(-__logf(ub[r]));
    y[r] = (acc[r] - lse + g) * 10.f;
    m2 = fmaxf(m2, y[r]);
  }
  float s2 = 0.f;
  #pragma unroll
  for (int r = 0; r < 8; ++r) { y[r] = __expf(y[r] - m2); s2 += y[r]; }
  const float inv = 1.f / s2;
  float* gz = genz + (size_t)b * 8 * 4096 + t;
  #pragma unroll
  for (int r = 0; r < 8; ++r) gz[(size_t)r * 4096] = y[r] * inv;
}

// MoE layer 0: hid[b,o,t] = sum_r z[b,r,t] * (pw0[r] @ pre[b,:,t] + pb0[r]).
// pre = h2[:, :, 8:]. Wave = 64 t, each wave does 64 of 256 output channels.
__global__ __launch_bounds__(256) void moe1_k(const float* __restrict__ h2,
    const float* __restrict__ genz, const float* __restrict__ pw0,
    const float* __restrict__ pb0, float* __restrict__ hid)
{
  __shared__ float pre_s[128][64];
  const int b = blockIdx.y;
  const int t0 = blockIdx.x * 64;
  const float* hb = h2 + (size_t)b * 128 * N2 + 8 + t0;
  for (int e = threadIdx.x; e < 128 * 64; e += 256) {
    int i = e >> 6, tt = e & 63;
    pre_s[i][tt] = hb[(size_t)i * N2 + tt];
  }
  __syncthreads();
  const int lane = threadIdx.x & 63;
  const int wv = threadIdx.x >> 6;
  float z[8];
  #pragma unroll
  for (int r = 0; r < 8; ++r)
    z[r] = genz[((size_t)b * 8 + r) * 4096 + t0 + lane];
  for (int k0 = 0; k0 < 64; k0 += 4) {
    const int oc0 = wv * 64 + k0;
    float dot[4][8];
    #pragma unroll
    for (int kk = 0; kk < 4; ++kk)
      #pragma unroll
      for (int r = 0; r < 8; ++r) dot[kk][r] = 0.f;
    #pragma unroll 2
    for (int i = 0; i < 128; ++i) {
      float v = pre_s[i][lane];
      #pragma unroll
      for (int kk = 0; kk < 4; ++kk)
        #pragma unroll
        for (int r = 0; r < 8; ++r)
          dot[kk][r] = fmaf(pw0[((size_t)r * 256 + oc0 + kk) * 128 + i], v, dot[kk][r]);
    }
    #pragma unroll
    for (int kk = 0; kk < 4; ++kk) {
      float h = 0.f;
      #pragma unroll
      for (int r = 0; r < 8; ++r)
        h = fmaf(z[r], dot[kk][r] + pb0[r * 256 + oc0 + kk], h);
      hid[((size_t)b * 256 + oc0 + kk) * 4096 + t0 + lane] = h;
    }
  }
}

// MoE layer 1 + output transforms. 512 threads, 8 waves, 8 oc each.
// hidden staged in 64-row LDS chunks; accumulators persist in registers.
__global__ __launch_bounds__(512) void moe2_k(const float* __restrict__ hid,
    const float* __restrict__ genz, const float* __restrict__ pw1,
    const float* __restrict__ pb1, float* __restrict__ out)
{
  __shared__ float hid_s[64][64];
  const int b = blockIdx.y;
  const int t0 = blockIdx.x * 64;
  const int lane = threadIdx.x & 63;
  const int wv = threadIdx.x >> 6;  // 0..7
  float z[8];
  #pragma unroll
  for (int r = 0; r < 8; ++r)
    z[r] = genz[((size_t)b * 8 + r) * 4096 + t0 + lane];
  const int oc0 = wv * 8;
  float dot[8][8];
  #pragma unroll
  for (int k = 0; k < 8; ++k)
    #pragma unroll
    for (int r = 0; r < 8; ++r) dot[k][r] = 0.f;
  for (int c = 0; c < 4; ++c) {
    __syncthreads();
    for (int e = threadIdx.x; e < 64 * 64; e += 512) {
      int i = e >> 6, tt = e & 63;
      hid_s[i][tt] = hid[((size_t)b * 256 + c * 64 + i) * 4096 + t0 + tt];
    }
    __syncthreads();
    #pragma unroll 2
    for (int i = 0; i < 64; ++i) {
      float v = hid_s[i][lane];
      #pragma unroll
      for (int k = 0; k < 8; ++k)
        #pragma unroll
        for (int r = 0; r < 8; ++r)
          dot[k][r] = fmaf(pw1[((size_t)r * 64 + oc0 + k) * 256 + c * 64 + i], v, dot[k][r]);
    }
  }
  const int t = t0 + lane;
  #pragma unroll
  for (int k = 0; k < 8; ++k) {
    float o = 0.f;
    #pragma unroll
    for (int r = 0; r < 8; ++r)
      o = fmaf(z[r], dot[k][r] + pb1[r * 64 + oc0 + k], o);
    const int oc = oc0 + k;
    if (oc < 32)
      out[((size_t)b * 32 + oc) * 4096 + t] = o;
    else
      out[(size_t)8 * 32 * 4096 + ((size_t)b * 32 + (oc - 32)) * 4096 + t] =
          0.5f + 0.5f * tanhf(o) + 0.001f;
  }
}

extern "C" void kernel_launch(void* const* d_in, const int* in_sizes, int n_in,
                              void* d_out, int out_size, void* d_ws, size_t ws_size,
                              hipStream_t stream) {
  const float* x   = (const float*)d_in[0];
  const float* u   = (const float*)d_in[1];
  const float* w0  = (const float*)d_in[2];
  const float* b0  = (const float*)d_in[3];
  const float* w1  = (const float*)d_in[4];
  const float* b1  = (const float*)d_in[5];
  const float* w2  = (const float*)d_in[6];
  const float* b2  = (const float*)d_in[7];
  const float* w3  = (const float*)d_in[8];
  const float* b3  = (const float*)d_in[9];
  const float* pw0 = (const float*)d_in[10];
  const float* pb0 = (const float*)d_in[11];
  const float* pw1 = (const float*)d_in[12];
  const float* pb1 = (const float*)d_in[13];

  float* out  = (float*)d_out;
  float* genz = out + (size_t)2 * 8 * 32 * 4096;   // third output, also MoE input

  float* ws   = (float*)d_ws;
  float* bufA = ws;                 // h0, later h2 (h0 dead by then)
  float* bufB = ws + 4208640;       // h1
  float* hid  = ws + 8415232;       // MoE hidden (8,256,4096)

  conv_k<32, 1, 15><<<dim3(65, 8), 256, 0, stream>>>(x,    w0, b0, bufA, 4096, N0);
  conv_k<128, 2, 0><<<dim3(65, 8), 256, 0, stream>>>(bufA, w1, b1, bufB, N0,   N1);
  conv_k<128, 4, 0><<<dim3(65, 8), 256, 0, stream>>>(bufB, w2, b2, bufA, N1,   N2);
  gumbel_k<<<128, 256, 0, stream>>>(bufA, w3, b3, u, genz);
  moe1_k<<<dim3(64, 8), 256, 0, stream>>>(bufA, genz, pw0, pb0, hid);
  moe2_k<<<dim3(64, 8), 512, 0, stream>>>(hid, genz, pw1, pb1, out);
}

// Round 4
// 250.195 us; speedup vs baseline: 13.4169x; 13.4169x over previous
//
#include <hip/hip_runtime.h>
#include <math.h>

typedef __attribute__((ext_vector_type(8))) short bf16x8;   // 8 bf16 = 4 VGPR
typedef __attribute__((ext_vector_type(4))) float f32x4;    // MFMA acc
struct __align__(8)  us4 { unsigned short x,y,z,w; };
struct __align__(16) ui4 { unsigned x,y,z,w; };

#define SLOPE 0.2291666666666667f
constexpr int N0=4110, N1=4108, N2=4104, NX=4111;

__device__ __forceinline__ unsigned short f2bf(float f){
  unsigned u = __float_as_uint(f);
  u = (u + 0x7FFF + ((u>>16)&1)) >> 16;   // RNE
  return (unsigned short)u;
}
__device__ __forceinline__ float bf2f(unsigned short h){
  return __uint_as_float(((unsigned)h)<<16);
}
__device__ __forceinline__ float rrelu(float v){ return v>=0.f ? v : v*SLOPE; }

// ---- weight repack to bf16 (k = tap*IC + i for convs; bias panels [o][32]) ----
__global__ __launch_bounds__(256) void prep_w(
  const float* __restrict__ w0, const float* __restrict__ w1, const float* __restrict__ w2,
  const float* __restrict__ pw0, const float* __restrict__ pw1,
  const float* __restrict__ pb0, const float* __restrict__ pb1,
  unsigned short* __restrict__ w0e, unsigned short* __restrict__ w1e, unsigned short* __restrict__ w2e,
  unsigned short* __restrict__ pw0b, unsigned short* __restrict__ pw1b,
  unsigned short* __restrict__ pb0e, unsigned short* __restrict__ pb1e)
{
  int idx = blockIdx.x*256 + threadIdx.x;
  if (idx < 8192){ int oc=idx>>6, k=idx&63, tap=k>>5, i=k&31;
    w0e[idx] = f2bf(w0[(oc*32+i)*2+tap]); return; }
  idx -= 8192;
  if (idx < 32768){ int oc=idx>>8, k=idx&255, tap=k>>7, i=k&127;
    w1e[idx] = f2bf(w1[(oc*128+i)*2+tap]); return; }
  idx -= 32768;
  if (idx < 32768){ int oc=idx>>8, k=idx&255, tap=k>>7, i=k&127;
    w2e[idx] = f2bf(w2[(oc*128+i)*2+tap]); return; }
  idx -= 32768;
  if (idx < 262144){ pw0b[idx] = f2bf(pw0[idx]); return; }
  idx -= 262144;
  if (idx < 131072){ pw1b[idx] = f2bf(pw1[idx]); return; }
  idx -= 131072;
  if (idx < 8192){ int o=idx>>5, r=idx&31; pb0e[idx] = r<8 ? f2bf(pb0[r*256+o]) : (unsigned short)0; return; }
  idx -= 8192;
  if (idx < 2048){ int o=idx>>5, r=idx&31; pb1e[idx] = r<8 ? f2bf(pb1[r*64+o]) : (unsigned short)0; return; }
}

// ---- x (B,32,4096) fp32 -> xt (B,4111,32) bf16, 15 zero-pad rows in front ----
__global__ __launch_bounds__(64) void prep_xt(const float* __restrict__ x,
                                              unsigned short* __restrict__ xt)
{
  __shared__ float s[32][64];
  const int b = blockIdx.y, j0 = blockIdx.x*64, l = threadIdx.x;
  #pragma unroll 4
  for (int i=0;i<32;i++){
    int p = j0 + l - 15;
    s[i][l] = (p>=0 && p<4096) ? x[((size_t)b*32+i)*4096+p] : 0.f;
  }
  __syncthreads();
  const int j = j0 + l;
  if (j < NX){
    unsigned tmp[16];
    #pragma unroll
    for (int q=0;q<16;q++)
      tmp[q] = (unsigned)f2bf(s[2*q][l]) | ((unsigned)f2bf(s[2*q+1][l])<<16);
    ui4* dst = (ui4*)(xt + ((size_t)b*NX + j)*32);
    #pragma unroll
    for (int q=0;q<4;q++){ ui4 v={tmp[4*q],tmp[4*q+1],tmp[4*q+2],tmp[4*q+3]}; dst[q]=v; }
  }
}

// ---- dilated k=2 conv as MFMA GEMM: out[o,t] = rrelu(b[o] + sum_k W[o,k]*act[t+tap*DIL, i]) ----
// block = 4 waves: 2 (o) x 2 (t); block tile 128o x 64t; wave tile 64o x 32t
template<int IC, int DIL, int NIN, int NOUT>
__global__ __launch_bounds__(256) void conv_g(
    const unsigned short* __restrict__ act,   // [8][NIN][IC]
    const unsigned short* __restrict__ wgt,   // [128][2*IC]
    const float* __restrict__ bias,           // [128]
    unsigned short* __restrict__ outp)        // [8][NOUT][128]
{
  constexpr int KT = 2*IC;
  constexpr int NK = KT/32;
  const int b  = blockIdx.y;
  const int tb = blockIdx.x*64;
  const int wid = threadIdx.x>>6, l = threadIdx.x&63;
  const int wr = wid>>1, wc = wid&1;
  const int o0 = wr*64;
  const int lo = l&15, hi = l>>4;

  bf16x8 bfr[2][NK];
  #pragma unroll
  for (int n=0;n<2;n++){
    int t = tb + wc*32 + n*16 + lo;
    int te = t < NOUT ? t : NOUT-1;
    #pragma unroll
    for (int kk=0;kk<NK;kk++){
      int k = kk*32 + hi*8;
      int tap = (k >= IC) ? 1 : 0;
      int off = k - tap*IC;
      bfr[n][kk] = *(const bf16x8*)(act + ((size_t)b*NIN + te + tap*DIL)*IC + off);
    }
  }
  f32x4 acc[4][2];
  #pragma unroll
  for (int m=0;m<4;m++)
    #pragma unroll
    for (int n=0;n<2;n++) acc[m][n] = (f32x4){0.f,0.f,0.f,0.f};

  #pragma unroll
  for (int kk=0;kk<NK;kk++){
    #pragma unroll
    for (int m=0;m<4;m++){
      bf16x8 af = *(const bf16x8*)(wgt + ((size_t)(o0+m*16+lo))*KT + kk*32 + hi*8);
      #pragma unroll
      for (int n=0;n<2;n++)
        acc[m][n] = __builtin_amdgcn_mfma_f32_16x16x32_bf16(af, bfr[n][kk], acc[m][n], 0,0,0);
    }
  }
  #pragma unroll
  for (int m=0;m<4;m++){
    const int ob2 = o0 + m*16 + hi*4;
    float b0v = bias[ob2+0], b1v = bias[ob2+1], b2v = bias[ob2+2], b3v = bias[ob2+3];
    #pragma unroll
    for (int n=0;n<2;n++){
      int t = tb + wc*32 + n*16 + lo;
      if (t < NOUT){
        us4 v;
        v.x = f2bf(rrelu(acc[m][n][0] + b0v));
        v.y = f2bf(rrelu(acc[m][n][1] + b1v));
        v.z = f2bf(rrelu(acc[m][n][2] + b2v));
        v.w = f2bf(rrelu(acc[m][n][3] + b3v));
        *(us4*)(outp + ((size_t)b*NOUT + t)*128 + ob2) = v;
      }
    }
  }
}

// ---- conv3(128->8,d=8) + rrelu + log-softmax + gumbel-softmax (fp32 math) ----
__global__ __launch_bounds__(64) void gumbel_g(
  const unsigned short* __restrict__ h2t,  // [8][N2][128] bf16
  const float* __restrict__ w3, const float* __restrict__ b3,
  const float* __restrict__ u,
  float* __restrict__ genz,                // [8][8][4096] fp32 (output 2)
  unsigned short* __restrict__ zt)         // [8][4096][32] bf16 (z padded to K=32)
{
  __shared__ unsigned hs[72][66];          // 72 t-rows x 128 bf16 (as 64 u32, pad 2)
  const int b = blockIdx.y, t0 = blockIdx.x*64, l = threadIdx.x;
  const unsigned* src = (const unsigned*)(h2t + ((size_t)b*N2 + t0)*128);
  for (int e=l; e<72*64; e+=64) hs[e>>6][e&63] = src[e];
  __syncthreads();

  float acc[8];
  #pragma unroll
  for (int r=0;r<8;r++) acc[r]=b3[r];
  for (int i2=0;i2<64;i2++){
    unsigned a0 = hs[l][i2], a1 = hs[l+8][i2];
    float v00 = bf2f(a0&0xffff), v01 = bf2f(a0>>16);
    float v10 = bf2f(a1&0xffff), v11 = bf2f(a1>>16);
    const int i = 2*i2;
    #pragma unroll
    for (int r=0;r<8;r++){
      acc[r] = fmaf(w3[(r*128+i)*2],     v00, acc[r]);
      acc[r] = fmaf(w3[(r*128+i)*2+1],   v10, acc[r]);
      acc[r] = fmaf(w3[(r*128+i+1)*2],   v01, acc[r]);
      acc[r] = fmaf(w3[(r*128+i+1)*2+1], v11, acc[r]);
    }
  }
  float m = -1e30f;
  #pragma unroll
  for (int r=0;r<8;r++){ acc[r] = rrelu(acc[r]); m = fmaxf(m, acc[r]); }
  float s = 0.f;
  #pragma unroll
  for (int r=0;r<8;r++) s += __expf(acc[r]-m);
  const float lse = m + __logf(s);
  const int t = t0 + l;
  const float* ub = u + ((size_t)b*4096 + t)*8;
  float y[8], m2 = -1e30f;
  #pragma unroll
  for (int r=0;r<8;r++){
    float g = -__logf(-__logf(ub[r]));
    y[r] = (acc[r] - lse + g)*10.f;
    m2 = fmaxf(m2, y[r]);
  }
  float s2 = 0.f;
  #pragma unroll
  for (int r=0;r<8;r++){ y[r] = __expf(y[r]-m2); s2 += y[r]; }
  const float inv = 1.f/s2;
  #pragma unroll
  for (int r=0;r<8;r++){
    y[r] *= inv;
    genz[((size_t)b*8+r)*4096 + t] = y[r];
  }
  ui4 zp = { (unsigned)f2bf(y[0]) | ((unsigned)f2bf(y[1])<<16),
             (unsigned)f2bf(y[2]) | ((unsigned)f2bf(y[3])<<16),
             (unsigned)f2bf(y[4]) | ((unsigned)f2bf(y[5])<<16),
             (unsigned)f2bf(y[6]) | ((unsigned)f2bf(y[7])<<16) };
  ui4 zz = {0,0,0,0};
  ui4* zd = (ui4*)(zt + ((size_t)b*4096 + t)*32);
  zd[0]=zp; zd[1]=zz; zd[2]=zz; zd[3]=zz;
}

// ---- MoE layer 0: hid[o,t] = sum_r z_r(t) * (pw0[r] @ pre)[o,t] + sum_r z_r(t)*pb0[r,o] ----
// bias via K=32 MFMA pb0e[o][r-pad] x zt[t][r-pad]. pre[t][i] = h2t[t+8][i]. K=128.
__global__ __launch_bounds__(256) void moe1_m(
  const unsigned short* __restrict__ h2t,  // [8][N2][128]
  const float* __restrict__ genz,
  const unsigned short* __restrict__ zt,   // [8][4096][32]
  const unsigned short* __restrict__ pw0b, // [8][256][128]
  const unsigned short* __restrict__ pb0e, // [256][32]
  unsigned short* __restrict__ hidt)       // [8][4096][256]
{
  __shared__ float zl[8][64];
  const int b = blockIdx.z, tb = blockIdx.y*64, ob = blockIdx.x*128;
  for (int e=threadIdx.x; e<512; e+=256)
    zl[e>>6][e&63] = genz[((size_t)b*8 + (e>>6))*4096 + tb + (e&63)];
  __syncthreads();
  const int wid=threadIdx.x>>6, l=threadIdx.x&63, lo=l&15, hi=l>>4;
  const int wr=wid>>1, wc=wid&1;
  const int o0 = ob + wr*64;

  bf16x8 bfr[2][4], zfr[2];
  #pragma unroll
  for (int n=0;n<2;n++){
    int t = tb + wc*32 + n*16 + lo;
    #pragma unroll
    for (int kk=0;kk<4;kk++)
      bfr[n][kk] = *(const bf16x8*)(h2t + ((size_t)b*N2 + t + 8)*128 + kk*32 + hi*8);
    zfr[n] = *(const bf16x8*)(zt + ((size_t)b*4096 + t)*32 + hi*8);
  }
  f32x4 acc[4][2];
  #pragma unroll
  for (int m=0;m<4;m++){
    bf16x8 pf = *(const bf16x8*)(pb0e + (size_t)(o0+m*16+lo)*32 + hi*8);
    #pragma unroll
    for (int n=0;n<2;n++)
      acc[m][n] = __builtin_amdgcn_mfma_f32_16x16x32_bf16(pf, zfr[n], (f32x4){0.f,0.f,0.f,0.f}, 0,0,0);
  }
  for (int r=0;r<8;r++){
    f32x4 ar[4][2];
    #pragma unroll
    for (int m=0;m<4;m++)
      #pragma unroll
      for (int n=0;n<2;n++) ar[m][n] = (f32x4){0.f,0.f,0.f,0.f};
    #pragma unroll
    for (int kk=0;kk<4;kk++){
      #pragma unroll
      for (int m=0;m<4;m++){
        bf16x8 af = *(const bf16x8*)(pw0b + ((size_t)r*256 + o0+m*16+lo)*128 + kk*32 + hi*8);
        #pragma unroll
        for (int n=0;n<2;n++)
          ar[m][n] = __builtin_amdgcn_mfma_f32_16x16x32_bf16(af, bfr[n][kk], ar[m][n], 0,0,0);
      }
    }
    #pragma unroll
    for (int n=0;n<2;n++){
      float zv = zl[r][wc*32 + n*16 + lo];
      #pragma unroll
      for (int m=0;m<4;m++)
        #pragma unroll
        for (int c=0;c<4;c++) acc[m][n][c] = fmaf(zv, ar[m][n][c], acc[m][n][c]);
    }
  }
  #pragma unroll
  for (int m=0;m<4;m++)
    #pragma unroll
    for (int n=0;n<2;n++){
      int t = tb + wc*32 + n*16 + lo;
      int o = o0 + m*16 + hi*4;
      us4 v;
      v.x=f2bf(acc[m][n][0]); v.y=f2bf(acc[m][n][1]); v.z=f2bf(acc[m][n][2]); v.w=f2bf(acc[m][n][3]);
      *(us4*)(hidt + ((size_t)b*4096 + t)*256 + o) = v;
    }
}

// ---- MoE layer 1 (+bias MFMA) + mus/sigmas transforms. K=256, M=64. wave tile 64o x 16t ----
__global__ __launch_bounds__(256) void moe2_m(
  const unsigned short* __restrict__ hidt, // [8][4096][256]
  const float* __restrict__ genz,
  const unsigned short* __restrict__ zt,
  const unsigned short* __restrict__ pw1b, // [8][64][256]
  const unsigned short* __restrict__ pb1e, // [64][32]
  float* __restrict__ out)
{
  __shared__ float zl[8][64];
  const int b = blockIdx.y, tb = blockIdx.x*64;
  for (int e=threadIdx.x; e<512; e+=256)
    zl[e>>6][e&63] = genz[((size_t)b*8 + (e>>6))*4096 + tb + (e&63)];
  __syncthreads();
  const int wid=threadIdx.x>>6, l=threadIdx.x&63, lo=l&15, hi=l>>4;
  const int tw = tb + wid*16;

  bf16x8 bfr[8];
  #pragma unroll
  for (int kk=0;kk<8;kk++)
    bfr[kk] = *(const bf16x8*)(hidt + ((size_t)b*4096 + tw + lo)*256 + kk*32 + hi*8);
  bf16x8 zfr = *(const bf16x8*)(zt + ((size_t)b*4096 + tw + lo)*32 + hi*8);

  f32x4 acc[4];
  #pragma unroll
  for (int m=0;m<4;m++){
    bf16x8 pf = *(const bf16x8*)(pb1e + (size_t)(m*16+lo)*32 + hi*8);
    acc[m] = __builtin_amdgcn_mfma_f32_16x16x32_bf16(pf, zfr, (f32x4){0.f,0.f,0.f,0.f}, 0,0,0);
  }
  for (int r=0;r<8;r++){
    f32x4 ar[4];
    #pragma unroll
    for (int m=0;m<4;m++) ar[m] = (f32x4){0.f,0.f,0.f,0.f};
    #pragma unroll
    for (int kk=0;kk<8;kk++){
      #pragma unroll
      for (int m=0;m<4;m++){
        bf16x8 af = *(const bf16x8*)(pw1b + ((size_t)r*64 + m*16+lo)*256 + kk*32 + hi*8);
        ar[m] = __builtin_amdgcn_mfma_f32_16x16x32_bf16(af, bfr[kk], ar[m], 0,0,0);
      }
    }
    float zv = zl[r][wid*16 + lo];
    #pragma unroll
    for (int m=0;m<4;m++)
      #pragma unroll
      for (int c=0;c<4;c++) acc[m][c] = fmaf(zv, ar[m][c], acc[m][c]);
  }
  const int t = tw + lo;
  #pragma unroll
  for (int m=0;m<4;m++)
    #pragma unroll
    for (int c=0;c<4;c++){
      int o = m*16 + hi*4 + c;
      float v = acc[m][c];
      if (o < 32)
        out[((size_t)b*32 + o)*4096 + t] = v;
      else {
        float e = __expf(2.f*v);
        float th = 1.f - 2.f/(e+1.f);
        out[(size_t)1048576 + ((size_t)b*32 + (o-32))*4096 + t] = 0.5f + 0.5f*th + 0.001f;
      }
    }
}

extern "C" void kernel_launch(void* const* d_in, const int* in_sizes, int n_in,
                              void* d_out, int out_size, void* d_ws, size_t ws_size,
                              hipStream_t stream) {
  const float* x   = (const float*)d_in[0];
  const float* u   = (const float*)d_in[1];
  const float* w0  = (const float*)d_in[2];
  const float* b0  = (const float*)d_in[3];
  const float* w1  = (const float*)d_in[4];
  const float* b1  = (const float*)d_in[5];
  const float* w2  = (const float*)d_in[6];
  const float* b2  = (const float*)d_in[7];
  const float* w3  = (const float*)d_in[8];
  const float* b3  = (const float*)d_in[9];
  const float* pw0 = (const float*)d_in[10];
  const float* pb0 = (const float*)d_in[11];
  const float* pw1 = (const float*)d_in[12];
  const float* pb1 = (const float*)d_in[13];

  float* out  = (float*)d_out;
  float* genz = out + (size_t)2*8*32*4096;

  char* p = (char*)d_ws;
  unsigned short* xt   = (unsigned short*)p; p += 2104832;   // 8*4111*32
  unsigned short* h0t  = (unsigned short*)p; p += 8417280;   // 8*4110*128
  unsigned short* h1t  = (unsigned short*)p; p += 8413184;   // 8*4108*128
  unsigned short* h2t  = (unsigned short*)p; p += 8404992;   // 8*4104*128
  unsigned short* ztb  = (unsigned short*)p; p += 2097152;   // 8*4096*32
  unsigned short* hidt = (unsigned short*)p; p += 16777216;  // 8*4096*256
  unsigned short* w0e  = (unsigned short*)p; p += 16384;
  unsigned short* w1e  = (unsigned short*)p; p += 65536;
  unsigned short* w2e  = (unsigned short*)p; p += 65536;
  unsigned short* pw0b = (unsigned short*)p; p += 524288;
  unsigned short* pw1b = (unsigned short*)p; p += 262144;
  unsigned short* pb0e = (unsigned short*)p; p += 16384;
  unsigned short* pb1e = (unsigned short*)p; p += 4096;

  prep_w<<<1864, 256, 0, stream>>>(w0,w1,w2,pw0,pw1,pb0,pb1,
                                   w0e,w1e,w2e,pw0b,pw1b,pb0e,pb1e);
  prep_xt<<<dim3(65,8), 64, 0, stream>>>(x, xt);
  conv_g<32,1,NX,N0><<<dim3(65,8), 256, 0, stream>>>(xt,  w0e, b0, h0t);
  conv_g<128,2,N0,N1><<<dim3(65,8), 256, 0, stream>>>(h0t, w1e, b1, h1t);
  conv_g<128,4,N1,N2><<<dim3(65,8), 256, 0, stream>>>(h1t, w2e, b2, h2t);
  gumbel_g<<<dim3(64,8), 64, 0, stream>>>(h2t, w3, b3, u, genz, ztb);
  moe1_m<<<dim3(2,64,8), 256, 0, stream>>>(h2t, genz, ztb, pw0b, pb0e, hidt);
  moe2_m<<<dim3(64,8), 256, 0, stream>>>(hidt, genz, ztb, pw1b, pb1e, out);
}

// Round 5
// 168.936 us; speedup vs baseline: 19.8704x; 1.4810x over previous
//
#include <hip/hip_runtime.h>
#include <math.h>

typedef __attribute__((ext_vector_type(8))) short bf16x8;   // 8 bf16 = 4 VGPR
typedef __attribute__((ext_vector_type(4))) float f32x4;    // MFMA acc
struct __align__(8)  us4 { unsigned short x,y,z,w; };
struct __align__(16) ui4 { unsigned x,y,z,w; };

#define SLOPE 0.2291666666666667f
constexpr int N0=4110, N1=4108, N2=4104, NX=4111;

__device__ __forceinline__ unsigned short f2bf(float f){
  unsigned u = __float_as_uint(f);
  u = (u + 0x7FFF + ((u>>16)&1)) >> 16;   // RNE
  return (unsigned short)u;
}
__device__ __forceinline__ float bf2f(unsigned short h){
  return __uint_as_float(((unsigned)h)<<16);
}
__device__ __forceinline__ float rrelu(float v){ return v>=0.f ? v : v*SLOPE; }

// ---- weight repack to bf16 (k = tap*IC + i for convs; bias panels [o][32]) ----
__global__ __launch_bounds__(256) void prep_w(
  const float* __restrict__ w0, const float* __restrict__ w1, const float* __restrict__ w2,
  const float* __restrict__ pw0, const float* __restrict__ pw1,
  const float* __restrict__ pb0, const float* __restrict__ pb1,
  unsigned short* __restrict__ w0e, unsigned short* __restrict__ w1e, unsigned short* __restrict__ w2e,
  unsigned short* __restrict__ pw0b, unsigned short* __restrict__ pw1b,
  unsigned short* __restrict__ pb0e, unsigned short* __restrict__ pb1e)
{
  int idx = blockIdx.x*256 + threadIdx.x;
  if (idx < 8192){ int oc=idx>>6, k=idx&63, tap=k>>5, i=k&31;
    w0e[idx] = f2bf(w0[(oc*32+i)*2+tap]); return; }
  idx -= 8192;
  if (idx < 32768){ int oc=idx>>8, k=idx&255, tap=k>>7, i=k&127;
    w1e[idx] = f2bf(w1[(oc*128+i)*2+tap]); return; }
  idx -= 32768;
  if (idx < 32768){ int oc=idx>>8, k=idx&255, tap=k>>7, i=k&127;
    w2e[idx] = f2bf(w2[(oc*128+i)*2+tap]); return; }
  idx -= 32768;
  if (idx < 262144){ pw0b[idx] = f2bf(pw0[idx]); return; }
  idx -= 262144;
  if (idx < 131072){ pw1b[idx] = f2bf(pw1[idx]); return; }
  idx -= 131072;
  if (idx < 8192){ int o=idx>>5, r=idx&31; pb0e[idx] = r<8 ? f2bf(pb0[r*256+o]) : (unsigned short)0; return; }
  idx -= 8192;
  if (idx < 2048){ int o=idx>>5, r=idx&31; pb1e[idx] = r<8 ? f2bf(pb1[r*64+o]) : (unsigned short)0; return; }
}

// ---- x (B,32,4096) fp32 -> xt (B,4111,32) bf16, 15 zero-pad rows in front ----
__global__ __launch_bounds__(64) void prep_xt(const float* __restrict__ x,
                                              unsigned short* __restrict__ xt)
{
  __shared__ float s[32][64];
  const int b = blockIdx.y, j0 = blockIdx.x*64, l = threadIdx.x;
  #pragma unroll 4
  for (int i=0;i<32;i++){
    int p = j0 + l - 15;
    s[i][l] = (p>=0 && p<4096) ? x[((size_t)b*32+i)*4096+p] : 0.f;
  }
  __syncthreads();
  const int j = j0 + l;
  if (j < NX){
    unsigned tmp[16];
    #pragma unroll
    for (int q=0;q<16;q++)
      tmp[q] = (unsigned)f2bf(s[2*q][l]) | ((unsigned)f2bf(s[2*q+1][l])<<16);
    ui4* dst = (ui4*)(xt + ((size_t)b*NX + j)*32);
    #pragma unroll
    for (int q=0;q<4;q++){ ui4 v={tmp[4*q],tmp[4*q+1],tmp[4*q+2],tmp[4*q+3]}; dst[q]=v; }
  }
}

// ---- dilated k=2 conv as MFMA GEMM, weights staged in LDS (XOR-swizzled) ----
// block = 4 waves: 2 (o) x 2 (t); block tile 128o x 64t; wave tile 64o x 32t
template<int IC, int DIL, int NIN, int NOUT>
__global__ __launch_bounds__(256) void conv_g(
    const unsigned short* __restrict__ act,   // [8][NIN][IC]
    const unsigned short* __restrict__ wgt,   // [128][2*IC]
    const float* __restrict__ bias,           // [128]
    unsigned short* __restrict__ outp)        // [8][NOUT][128]
{
  constexpr int KT  = 2*IC;
  constexpr int NK  = KT/32;
  constexpr int RB  = KT*2;       // weight row bytes
  constexpr int CPR = RB/16;      // 16B chunks per row
  constexpr int NCH = 128*CPR;
  __shared__ __align__(16) char wsm[128*RB];

  const int tid = threadIdx.x;
  // stage weights once, swizzled (row-stride RB is a 32-bank multiple -> swizzle needed)
  for (int c = tid; c < NCH; c += 256){
    int row = c / CPR, cc = c % CPR;
    ui4 v = *(const ui4*)((const char*)wgt + row*RB + cc*16);
    *(ui4*)(wsm + row*RB + ((cc*16) ^ ((row&7)<<4))) = v;
  }

  const int b  = blockIdx.y;
  const int tb = blockIdx.x*64;
  const int wid = tid>>6, l = tid&63;
  const int wr = wid>>1, wc = wid&1;
  const int o0 = wr*64;
  const int lo = l&15, hi = l>>4;

  bf16x8 bfr[2][NK];
  #pragma unroll
  for (int n=0;n<2;n++){
    int t = tb + wc*32 + n*16 + lo;
    int te = t < NOUT ? t : NOUT-1;
    #pragma unroll
    for (int kk=0;kk<NK;kk++){
      int k = kk*32 + hi*8;
      int tap = (k >= IC) ? 1 : 0;
      int off = k - tap*IC;
      bfr[n][kk] = *(const bf16x8*)(act + ((size_t)b*NIN + te + tap*DIL)*IC + off);
    }
  }
  __syncthreads();

  f32x4 acc[4][2];
  #pragma unroll
  for (int m=0;m<4;m++)
    #pragma unroll
    for (int n=0;n<2;n++) acc[m][n] = (f32x4){0.f,0.f,0.f,0.f};

  #pragma unroll
  for (int kk=0;kk<NK;kk++){
    #pragma unroll
    for (int m=0;m<4;m++){
      int row = o0 + m*16 + lo;
      int kb  = kk*64 + hi*16;
      bf16x8 af = *(const bf16x8*)(wsm + row*RB + (kb ^ ((row&7)<<4)));
      #pragma unroll
      for (int n=0;n<2;n++)
        acc[m][n] = __builtin_amdgcn_mfma_f32_16x16x32_bf16(af, bfr[n][kk], acc[m][n], 0,0,0);
    }
  }
  #pragma unroll
  for (int m=0;m<4;m++){
    const int ob2 = o0 + m*16 + hi*4;
    float b0v = bias[ob2+0], b1v = bias[ob2+1], b2v = bias[ob2+2], b3v = bias[ob2+3];
    #pragma unroll
    for (int n=0;n<2;n++){
      int t = tb + wc*32 + n*16 + lo;
      if (t < NOUT){
        us4 v;
        v.x = f2bf(rrelu(acc[m][n][0] + b0v));
        v.y = f2bf(rrelu(acc[m][n][1] + b1v));
        v.z = f2bf(rrelu(acc[m][n][2] + b2v));
        v.w = f2bf(rrelu(acc[m][n][3] + b3v));
        *(us4*)(outp + ((size_t)b*NOUT + t)*128 + ob2) = v;
      }
    }
  }
}

// ---- conv3(128->8,d=8) + rrelu + log-softmax + gumbel-softmax (fp32 math) ----
__global__ __launch_bounds__(64) void gumbel_g(
  const unsigned short* __restrict__ h2t,  // [8][N2][128] bf16
  const float* __restrict__ w3, const float* __restrict__ b3,
  const float* __restrict__ u,
  float* __restrict__ genz,                // [8][8][4096] fp32 (output 2)
  unsigned short* __restrict__ zt)         // [8][4096][32] bf16 (z padded to K=32)
{
  __shared__ unsigned hs[72][66];          // 72 t-rows x 128 bf16 (as 64 u32, pad 2)
  const int b = blockIdx.y, t0 = blockIdx.x*64, l = threadIdx.x;
  const unsigned* src = (const unsigned*)(h2t + ((size_t)b*N2 + t0)*128);
  for (int e=l; e<72*64; e+=64) hs[e>>6][e&63] = src[e];
  __syncthreads();

  float acc[8];
  #pragma unroll
  for (int r=0;r<8;r++) acc[r]=b3[r];
  for (int i2=0;i2<64;i2++){
    unsigned a0 = hs[l][i2], a1 = hs[l+8][i2];
    float v00 = bf2f(a0&0xffff), v01 = bf2f(a0>>16);
    float v10 = bf2f(a1&0xffff), v11 = bf2f(a1>>16);
    const int i = 2*i2;
    #pragma unroll
    for (int r=0;r<8;r++){
      acc[r] = fmaf(w3[(r*128+i)*2],     v00, acc[r]);
      acc[r] = fmaf(w3[(r*128+i)*2+1],   v10, acc[r]);
      acc[r] = fmaf(w3[(r*128+i+1)*2],   v01, acc[r]);
      acc[r] = fmaf(w3[(r*128+i+1)*2+1], v11, acc[r]);
    }
  }
  float m = -1e30f;
  #pragma unroll
  for (int r=0;r<8;r++){ acc[r] = rrelu(acc[r]); m = fmaxf(m, acc[r]); }
  float s = 0.f;
  #pragma unroll
  for (int r=0;r<8;r++) s += __expf(acc[r]-m);
  const float lse = m + __logf(s);
  const int t = t0 + l;
  const float* ub = u + ((size_t)b*4096 + t)*8;
  float y[8], m2 = -1e30f;
  #pragma unroll
  for (int r=0;r<8;r++){
    float g = -__logf(-__logf(ub[r]));
    y[r] = (acc[r] - lse + g)*10.f;
    m2 = fmaxf(m2, y[r]);
  }
  float s2 = 0.f;
  #pragma unroll
  for (int r=0;r<8;r++){ y[r] = __expf(y[r]-m2); s2 += y[r]; }
  const float inv = 1.f/s2;
  #pragma unroll
  for (int r=0;r<8;r++){
    y[r] *= inv;
    genz[((size_t)b*8+r)*4096 + t] = y[r];
  }
  ui4 zp = { (unsigned)f2bf(y[0]) | ((unsigned)f2bf(y[1])<<16),
             (unsigned)f2bf(y[2]) | ((unsigned)f2bf(y[3])<<16),
             (unsigned)f2bf(y[4]) | ((unsigned)f2bf(y[5])<<16),
             (unsigned)f2bf(y[6]) | ((unsigned)f2bf(y[7])<<16) };
  ui4 zz = {0,0,0,0};
  ui4* zd = (ui4*)(zt + ((size_t)b*4096 + t)*32);
  zd[0]=zp; zd[1]=zz; zd[2]=zz; zd[3]=zz;
}

// ---- MoE layer 0, LDS-staged: hid[o,t] = sum_r z_rt*(W0_r@pre + b0_r)[o,t] ----
// 8 waves = 4(o) x 2(t); block tile o128 x t128; wave o32 x t64 (m2 x n4).
// Per r: A-panel (o128 x K128 = 32KB) double-buffered in LDS, XOR-swizzled,
// reg-staged issue-early/write-late so next panel's L2 latency hides under MFMAs.
__global__ __launch_bounds__(512) void moe1_m(
  const unsigned short* __restrict__ h2t,  // [8][N2][128]
  const float* __restrict__ genz,
  const unsigned short* __restrict__ zt,   // [8][4096][32]
  const unsigned short* __restrict__ pw0b, // [8][256][128]
  const unsigned short* __restrict__ pb0e, // [256][32]
  unsigned short* __restrict__ hidt)       // [8][4096][256]
{
  __shared__ __align__(16) char smem[65536 + 4096];
  char* abuf0 = smem;
  char* abuf1 = smem + 32768;
  float* zl = (float*)(smem + 65536);      // [8][128]

  const int b = blockIdx.z, tb = blockIdx.y*128, ob = blockIdx.x*128;
  const int tid = threadIdx.x;
  for (int e = tid; e < 1024; e += 512)
    zl[e] = genz[((size_t)b*8 + (e>>7))*4096 + tb + (e&127)];

  const int wid = tid>>6, l = tid&63, lo = l&15, hi = l>>4;
  const int wo = wid&3, wt = wid>>2;

  // B fragments (held whole kernel) + bias accumulator via K=32 MFMA on z
  bf16x8 bfr[4][4], zfr[4];
  #pragma unroll
  for (int n=0;n<4;n++){
    int t = tb + wt*64 + n*16 + lo;
    #pragma unroll
    for (int kk=0;kk<4;kk++)
      bfr[n][kk] = *(const bf16x8*)(h2t + ((size_t)b*N2 + t + 8)*128 + kk*32 + hi*8);
    zfr[n] = *(const bf16x8*)(zt + ((size_t)b*4096 + t)*32 + hi*8);
  }
  f32x4 acc[2][4];
  #pragma unroll
  for (int m=0;m<2;m++){
    bf16x8 pf = *(const bf16x8*)(pb0e + (size_t)(ob + wo*32 + m*16 + lo)*32 + hi*8);
    #pragma unroll
    for (int n=0;n<4;n++)
      acc[m][n] = __builtin_amdgcn_mfma_f32_16x16x32_bf16(pf, zfr[n], (f32x4){0.f,0.f,0.f,0.f}, 0,0,0);
  }

  // prologue: stage r=0 into abuf0 (linear global read, swizzled LDS write)
  {
    const char* src = (const char*)(pw0b + (size_t)ob*128);
    #pragma unroll
    for (int i=0;i<4;i++){
      int c = tid + i*512, row = c>>4, cc = c&15;
      ui4 v = *(const ui4*)(src + row*256 + cc*16);
      *(ui4*)(abuf0 + row*256 + ((cc*16) ^ ((row&7)<<4))) = v;
    }
  }
  __syncthreads();

  #pragma unroll
  for (int r=0;r<8;r++){
    char* cur = (r&1) ? abuf1 : abuf0;
    char* nxt = (r&1) ? abuf0 : abuf1;
    ui4 stg[4];
    if (r < 7){
      const char* src = (const char*)(pw0b + ((size_t)(r+1)*256 + ob)*128);
      #pragma unroll
      for (int i=0;i<4;i++){
        int c = tid + i*512;
        stg[i] = *(const ui4*)(src + (c>>4)*256 + (c&15)*16);
      }
    }
    f32x4 ar[2][4];
    #pragma unroll
    for (int m=0;m<2;m++)
      #pragma unroll
      for (int n=0;n<4;n++) ar[m][n] = (f32x4){0.f,0.f,0.f,0.f};
    #pragma unroll
    for (int kk=0;kk<4;kk++){
      #pragma unroll
      for (int m=0;m<2;m++){
        int row = wo*32 + m*16 + lo;
        int kb  = kk*64 + hi*16;
        bf16x8 af = *(const bf16x8*)(cur + row*256 + (kb ^ ((row&7)<<4)));
        #pragma unroll
        for (int n=0;n<4;n++)
          ar[m][n] = __builtin_amdgcn_mfma_f32_16x16x32_bf16(af, bfr[n][kk], ar[m][n], 0,0,0);
      }
    }
    #pragma unroll
    for (int n=0;n<4;n++){
      float zv = zl[r*128 + wt*64 + n*16 + lo];
      #pragma unroll
      for (int m=0;m<2;m++)
        #pragma unroll
        for (int c2=0;c2<4;c2++)
          acc[m][n][c2] = fmaf(zv, ar[m][n][c2], acc[m][n][c2]);
    }
    if (r < 7){
      #pragma unroll
      for (int i=0;i<4;i++){
        int c = tid + i*512;
        *(ui4*)(nxt + (c>>4)*256 + (((c&15)*16) ^ (((c>>4)&7)<<4))) = stg[i];
      }
    }
    __syncthreads();
  }

  #pragma unroll
  for (int m=0;m<2;m++){
    int o = ob + wo*32 + m*16 + hi*4;
    #pragma unroll
    for (int n=0;n<4;n++){
      int t = tb + wt*64 + n*16 + lo;
      us4 v;
      v.x=f2bf(acc[m][n][0]); v.y=f2bf(acc[m][n][1]);
      v.z=f2bf(acc[m][n][2]); v.w=f2bf(acc[m][n][3]);
      *(us4*)(hidt + ((size_t)b*4096 + t)*256 + o) = v;
    }
  }
}

// ---- MoE layer 1, LDS-staged, K split across wave pairs; epilogue LDS-reduce ----
// 8 waves = 2(o) x 2(t) x 2(k); block tile o64 x t64; wave o32 x t32 x K128.
__global__ __launch_bounds__(512) void moe2_m(
  const unsigned short* __restrict__ hidt, // [8][4096][256]
  const float* __restrict__ genz,
  const unsigned short* __restrict__ zt,
  const unsigned short* __restrict__ pw1b, // [8][64][256]
  const unsigned short* __restrict__ pb1e, // [64][32]
  float* __restrict__ out)
{
  __shared__ __align__(16) char smem[65536 + 2048];
  char* abuf0 = smem;
  char* abuf1 = smem + 32768;
  float* zl  = (float*)(smem + 65536);     // [8][64]
  float* red = (float*)smem;               // overlaps abuf0; used after final barrier

  const int b = blockIdx.y, tb = blockIdx.x*64;
  const int tid = threadIdx.x;
  for (int e = tid; e < 512; e += 512)
    zl[e] = genz[((size_t)b*8 + (e>>6))*4096 + tb + (e&63)];

  const int wid = tid>>6, l = tid&63, lo = l&15, hi = l>>4;
  const int wo = wid&1, wt = (wid>>1)&1, wk = wid>>2;

  bf16x8 bfr[2][4];
  #pragma unroll
  for (int n=0;n<2;n++){
    int t = tb + wt*32 + n*16 + lo;
    #pragma unroll
    for (int kk=0;kk<4;kk++)
      bfr[n][kk] = *(const bf16x8*)(hidt + ((size_t)b*4096 + t)*256 + wk*128 + kk*32 + hi*8);
  }
  f32x4 acc[2][2];
  if (wk == 0){
    #pragma unroll
    for (int m=0;m<2;m++){
      bf16x8 pf = *(const bf16x8*)(pb1e + (size_t)(wo*32 + m*16 + lo)*32 + hi*8);
      #pragma unroll
      for (int n=0;n<2;n++){
        bf16x8 zf = *(const bf16x8*)(zt + ((size_t)b*4096 + tb + wt*32 + n*16 + lo)*32 + hi*8);
        acc[m][n] = __builtin_amdgcn_mfma_f32_16x16x32_bf16(pf, zf, (f32x4){0.f,0.f,0.f,0.f}, 0,0,0);
      }
    }
  } else {
    #pragma unroll
    for (int m=0;m<2;m++)
      #pragma unroll
      for (int n=0;n<2;n++) acc[m][n] = (f32x4){0.f,0.f,0.f,0.f};
  }

  {
    const char* src = (const char*)pw1b;
    #pragma unroll
    for (int i=0;i<4;i++){
      int c = tid + i*512, row = c>>5, cc = c&31;
      ui4 v = *(const ui4*)(src + row*512 + cc*16);
      *(ui4*)(abuf0 + row*512 + ((cc*16) ^ ((row&7)<<4))) = v;
    }
  }
  __syncthreads();

  #pragma unroll
  for (int r=0;r<8;r++){
    char* cur = (r&1) ? abuf1 : abuf0;
    char* nxt = (r&1) ? abuf0 : abuf1;
    ui4 stg[4];
    if (r < 7){
      const char* src = (const char*)(pw1b + (size_t)(r+1)*64*256);
      #pragma unroll
      for (int i=0;i<4;i++){
        int c = tid + i*512;
        stg[i] = *(const ui4*)(src + (c>>5)*512 + (c&31)*16);
      }
    }
    f32x4 ar[2][2];
    #pragma unroll
    for (int m=0;m<2;m++)
      #pragma unroll
      for (int n=0;n<2;n++) ar[m][n] = (f32x4){0.f,0.f,0.f,0.f};
    #pragma unroll
    for (int kk=0;kk<4;kk++){
      #pragma unroll
      for (int m=0;m<2;m++){
        int row = wo*32 + m*16 + lo;
        int kb  = wk*256 + kk*64 + hi*16;
        bf16x8 af = *(const bf16x8*)(cur + row*512 + (kb ^ ((row&7)<<4)));
        #pragma unroll
        for (int n=0;n<2;n++)
          ar[m][n] = __builtin_amdgcn_mfma_f32_16x16x32_bf16(af, bfr[n][kk], ar[m][n], 0,0,0);
      }
    }
    #pragma unroll
    for (int n=0;n<2;n++){
      float zv = zl[r*64 + wt*32 + n*16 + lo];
      #pragma unroll
      for (int m=0;m<2;m++)
        #pragma unroll
        for (int c2=0;c2<4;c2++)
          acc[m][n][c2] = fmaf(zv, ar[m][n][c2], acc[m][n][c2]);
    }
    if (r < 7){
      #pragma unroll
      for (int i=0;i<4;i++){
        int c = tid + i*512;
        *(ui4*)(nxt + (c>>5)*512 + (((c&31)*16) ^ (((c>>5)&7)<<4))) = stg[i];
      }
    }
    __syncthreads();
  }

  // k-split reduction through LDS (row pad 65 to dodge bank aliasing)
  if (wk == 1){
    #pragma unroll
    for (int m=0;m<2;m++)
      #pragma unroll
      for (int n=0;n<2;n++)
        #pragma unroll
        for (int c2=0;c2<4;c2++)
          red[(wo*32 + m*16 + hi*4 + c2)*65 + wt*32 + n*16 + lo] = acc[m][n][c2];
  }
  __syncthreads();
  if (wk == 0){
    #pragma unroll
    for (int m=0;m<2;m++){
      #pragma unroll
      for (int n=0;n<2;n++){
        int t = tb + wt*32 + n*16 + lo;
        #pragma unroll
        for (int c2=0;c2<4;c2++){
          int o = wo*32 + m*16 + hi*4 + c2;
          float v = acc[m][n][c2] + red[o*65 + wt*32 + n*16 + lo];
          if (o < 32)
            out[((size_t)b*32 + o)*4096 + t] = v;
          else {
            float e = __expf(2.f*v);
            float th = 1.f - 2.f/(e+1.f);
            out[(size_t)1048576 + ((size_t)b*32 + (o-32))*4096 + t] = 0.5f + 0.5f*th + 0.001f;
          }
        }
      }
    }
  }
}

extern "C" void kernel_launch(void* const* d_in, const int* in_sizes, int n_in,
                              void* d_out, int out_size, void* d_ws, size_t ws_size,
                              hipStream_t stream) {
  const float* x   = (const float*)d_in[0];
  const float* u   = (const float*)d_in[1];
  const float* w0  = (const float*)d_in[2];
  const float* b0  = (const float*)d_in[3];
  const float* w1  = (const float*)d_in[4];
  const float* b1  = (const float*)d_in[5];
  const float* w2  = (const float*)d_in[6];
  const float* b2  = (const float*)d_in[7];
  const float* w3  = (const float*)d_in[8];
  const float* b3  = (const float*)d_in[9];
  const float* pw0 = (const float*)d_in[10];
  const float* pb0 = (const float*)d_in[11];
  const float* pw1 = (const float*)d_in[12];
  const float* pb1 = (const float*)d_in[13];

  float* out  = (float*)d_out;
  float* genz = out + (size_t)2*8*32*4096;

  char* p = (char*)d_ws;
  unsigned short* xt   = (unsigned short*)p; p += 2104832;   // 8*4111*32
  unsigned short* h0t  = (unsigned short*)p; p += 8417280;   // 8*4110*128
  unsigned short* h1t  = (unsigned short*)p; p += 8413184;   // 8*4108*128
  unsigned short* h2t  = (unsigned short*)p; p += 8404992;   // 8*4104*128
  unsigned short* ztb  = (unsigned short*)p; p += 2097152;   // 8*4096*32
  unsigned short* hidt = (unsigned short*)p; p += 16777216;  // 8*4096*256
  unsigned short* w0e  = (unsigned short*)p; p += 16384;
  unsigned short* w1e  = (unsigned short*)p; p += 65536;
  unsigned short* w2e  = (unsigned short*)p; p += 65536;
  unsigned short* pw0b = (unsigned short*)p; p += 524288;
  unsigned short* pw1b = (unsigned short*)p; p += 262144;
  unsigned short* pb0e = (unsigned short*)p; p += 16384;
  unsigned short* pb1e = (unsigned short*)p; p += 4096;

  prep_w<<<1864, 256, 0, stream>>>(w0,w1,w2,pw0,pw1,pb0,pb1,
                                   w0e,w1e,w2e,pw0b,pw1b,pb0e,pb1e);
  prep_xt<<<dim3(65,8), 64, 0, stream>>>(x, xt);
  conv_g<32,1,NX,N0><<<dim3(65,8), 256, 0, stream>>>(xt,  w0e, b0, h0t);
  conv_g<128,2,N0,N1><<<dim3(65,8), 256, 0, stream>>>(h0t, w1e, b1, h1t);
  conv_g<128,4,N1,N2><<<dim3(65,8), 256, 0, stream>>>(h1t, w2e, b2, h2t);
  gumbel_g<<<dim3(64,8), 64, 0, stream>>>(h2t, w3, b3, u, genz, ztb);
  moe1_m<<<dim3(2,32,8), 512, 0, stream>>>(h2t, genz, ztb, pw0b, pb0e, hidt);
  moe2_m<<<dim3(64,8), 512, 0, stream>>>(hidt, genz, ztb, pw1b, pb1e, out);
}

// Round 7
// 168.581 us; speedup vs baseline: 19.9123x; 1.0021x over previous
//
#include <hip/hip_runtime.h>
#include <math.h>

typedef __attribute__((ext_vector_type(8))) short bf16x8;   // 8 bf16 = 4 VGPR
typedef __attribute__((ext_vector_type(4))) float f32x4;    // MFMA acc
typedef __attribute__((ext_vector_type(4))) unsigned uix4;  // for NT stores
struct __align__(8)  us4 { unsigned short x,y,z,w; };
struct __align__(16) ui4 { unsigned x,y,z,w; };

#define SLOPE 0.2291666666666667f
constexpr int N0=4110, N1=4108, N2=4104, NX=4111;

__device__ __forceinline__ unsigned short f2bf(float f){
  unsigned u = __float_as_uint(f);
  u = (u + 0x7FFF + ((u>>16)&1)) >> 16;   // RNE
  return (unsigned short)u;
}
__device__ __forceinline__ float bf2f(unsigned short h){
  return __uint_as_float(((unsigned)h)<<16);
}
__device__ __forceinline__ float rrelu(float v){ return v>=0.f ? v : v*SLOPE; }
__device__ __forceinline__ void st_nt(void* p, ui4 v){
  __builtin_nontemporal_store(*(const uix4*)&v, (uix4*)p);
}
__device__ __forceinline__ bf16x8 ld_nt(const bf16x8* p){ return __builtin_nontemporal_load(p); }

// ---- weight repack to bf16 (k = tap*IC + i for convs; bias panels [o][32]) ----
__global__ __launch_bounds__(256) void prep_w(
  const float* __restrict__ w0, const float* __restrict__ w1, const float* __restrict__ w2,
  const float* __restrict__ pw0, const float* __restrict__ pw1,
  const float* __restrict__ pb0, const float* __restrict__ pb1,
  unsigned short* __restrict__ w0e, unsigned short* __restrict__ w1e, unsigned short* __restrict__ w2e,
  unsigned short* __restrict__ pw0b, unsigned short* __restrict__ pw1b,
  unsigned short* __restrict__ pb0e, unsigned short* __restrict__ pb1e)
{
  int idx = blockIdx.x*256 + threadIdx.x;
  if (idx < 8192){ int oc=idx>>6, k=idx&63, tap=k>>5, i=k&31;
    w0e[idx] = f2bf(w0[(oc*32+i)*2+tap]); return; }
  idx -= 8192;
  if (idx < 32768){ int oc=idx>>8, k=idx&255, tap=k>>7, i=k&127;
    w1e[idx] = f2bf(w1[(oc*128+i)*2+tap]); return; }
  idx -= 32768;
  if (idx < 32768){ int oc=idx>>8, k=idx&255, tap=k>>7, i=k&127;
    w2e[idx] = f2bf(w2[(oc*128+i)*2+tap]); return; }
  idx -= 32768;
  if (idx < 262144){ pw0b[idx] = f2bf(pw0[idx]); return; }
  idx -= 262144;
  if (idx < 131072){ pw1b[idx] = f2bf(pw1[idx]); return; }
  idx -= 131072;
  if (idx < 8192){ int o=idx>>5, r=idx&31; pb0e[idx] = r<8 ? f2bf(pb0[r*256+o]) : (unsigned short)0; return; }
  idx -= 8192;
  if (idx < 2048){ int o=idx>>5, r=idx&31; pb1e[idx] = r<8 ? f2bf(pb1[r*64+o]) : (unsigned short)0; return; }
}

// ---- x (B,32,4096) fp32 -> xt (B,4111,32) bf16, 15 zero-pad rows in front ----
__global__ __launch_bounds__(64) void prep_xt(const float* __restrict__ x,
                                              unsigned short* __restrict__ xt)
{
  __shared__ float s[32][64];
  const int b = blockIdx.y, j0 = blockIdx.x*64, l = threadIdx.x;
  #pragma unroll 4
  for (int i=0;i<32;i++){
    int p = j0 + l - 15;
    s[i][l] = (p>=0 && p<4096) ? x[((size_t)b*32+i)*4096+p] : 0.f;
  }
  __syncthreads();
  const int j = j0 + l;
  if (j < NX){
    unsigned tmp[16];
    #pragma unroll
    for (int q=0;q<16;q++)
      tmp[q] = (unsigned)f2bf(s[2*q][l]) | ((unsigned)f2bf(s[2*q+1][l])<<16);
    ui4* dst = (ui4*)(xt + ((size_t)b*NX + j)*32);
    #pragma unroll
    for (int q=0;q<4;q++){ ui4 v={tmp[4*q],tmp[4*q+1],tmp[4*q+2],tmp[4*q+3]}; dst[q]=v; }
  }
}

// ---- dilated k=2 conv as MFMA GEMM, weights in LDS; output coalesced via LDS ----
// block = 4 waves: 2 (o) x 2 (t); block tile 128o x 64t; wave tile 64o x 32t
template<int IC, int DIL, int NIN, int NOUT>
__global__ __launch_bounds__(256) void conv_g(
    const unsigned short* __restrict__ act,   // [8][NIN][IC]
    const unsigned short* __restrict__ wgt,   // [128][2*IC]
    const float* __restrict__ bias,           // [128]
    unsigned short* __restrict__ outp)        // [8][NOUT][128]
{
  constexpr int KT  = 2*IC;
  constexpr int NK  = KT/32;
  constexpr int RB  = KT*2;       // weight row bytes
  constexpr int CPR = RB/16;      // 16B chunks per row
  constexpr int NCH = 128*CPR;
  __shared__ __align__(16) char wsm[128*RB];
  __shared__ __align__(16) char outs[64*256];   // [t64][o128] bf16, swizzled

  const int tid = threadIdx.x;
  for (int c = tid; c < NCH; c += 256){
    int row = c / CPR, cc = c % CPR;
    ui4 v = *(const ui4*)((const char*)wgt + row*RB + cc*16);
    *(ui4*)(wsm + row*RB + ((cc*16) ^ ((row&7)<<4))) = v;
  }

  const int b  = blockIdx.y;
  const int tb = blockIdx.x*64;
  const int wid = tid>>6, l = tid&63;
  const int wr = wid>>1, wc = wid&1;
  const int o0 = wr*64;
  const int lo = l&15, hi = l>>4;

  bf16x8 bfr[2][NK];
  #pragma unroll
  for (int n=0;n<2;n++){
    int t = tb + wc*32 + n*16 + lo;
    int te = t < NOUT ? t : NOUT-1;
    #pragma unroll
    for (int kk=0;kk<NK;kk++){
      int k = kk*32 + hi*8;
      int tap = (k >= IC) ? 1 : 0;
      int off = k - tap*IC;
      bfr[n][kk] = *(const bf16x8*)(act + ((size_t)b*NIN + te + tap*DIL)*IC + off);
    }
  }
  __syncthreads();

  f32x4 acc[4][2];
  #pragma unroll
  for (int m=0;m<4;m++)
    #pragma unroll
    for (int n=0;n<2;n++) acc[m][n] = (f32x4){0.f,0.f,0.f,0.f};

  #pragma unroll
  for (int kk=0;kk<NK;kk++){
    #pragma unroll
    for (int m=0;m<4;m++){
      int row = o0 + m*16 + lo;
      int kb  = kk*64 + hi*16;
      bf16x8 af = *(const bf16x8*)(wsm + row*RB + (kb ^ ((row&7)<<4)));
      #pragma unroll
      for (int n=0;n<2;n++)
        acc[m][n] = __builtin_amdgcn_mfma_f32_16x16x32_bf16(af, bfr[n][kk], acc[m][n], 0,0,0);
    }
  }
  // stage output tile in LDS ([t][o], XOR-swizzled 16B slots)
  #pragma unroll
  for (int m=0;m<4;m++){
    const int ob2 = o0 + m*16 + hi*4;
    float b0v = bias[ob2+0], b1v = bias[ob2+1], b2v = bias[ob2+2], b3v = bias[ob2+3];
    #pragma unroll
    for (int n=0;n<2;n++){
      int tl = wc*32 + n*16 + lo;
      us4 v;
      v.x = f2bf(rrelu(acc[m][n][0] + b0v));
      v.y = f2bf(rrelu(acc[m][n][1] + b1v));
      v.z = f2bf(rrelu(acc[m][n][2] + b2v));
      v.w = f2bf(rrelu(acc[m][n][3] + b3v));
      *(us4*)(outs + tl*256 + ((ob2*2) ^ ((tl&7)<<4))) = v;
    }
  }
  __syncthreads();
  // coalesced writeout: 256B-contiguous runs per t-row
  #pragma unroll
  for (int i=0;i<4;i++){
    int c = tid + i*256;
    int row = c>>4, cc = c&15;
    if (tb + row < NOUT){
      ui4 v = *(const ui4*)(outs + row*256 + ((cc*16) ^ ((row&7)<<4)));
      *(ui4*)(outp + ((size_t)b*NOUT + tb + row)*128 + cc*8) = v;
    }
  }
}

// ---- conv3(128->8,d=8) + rrelu + log-softmax + gumbel-softmax (fp32 math) ----
// 256 threads, t-tile 256, one thread per t.
__global__ __launch_bounds__(256) void gumbel_g(
  const unsigned short* __restrict__ h2t,  // [8][N2][128] bf16
  const float* __restrict__ w3, const float* __restrict__ b3,
  const float* __restrict__ u,
  float* __restrict__ genz,                // [8][8][4096] fp32 (output 2)
  unsigned short* __restrict__ zt)         // [8][4096][32] bf16 (z padded to K=32)
{
  __shared__ unsigned hs[264][67];         // 264 t-rows x 128 bf16 (64 u32, pad->67)
  const int b = blockIdx.y, t0 = blockIdx.x*256, l = threadIdx.x;
  const unsigned* src = (const unsigned*)(h2t + ((size_t)b*N2 + t0)*128);
  for (int e=l; e<264*64; e+=256) hs[e>>6][e&63] = src[e];
  __syncthreads();

  float acc[8];
  #pragma unroll
  for (int r=0;r<8;r++) acc[r]=b3[r];
  for (int i2=0;i2<64;i2++){
    unsigned a0 = hs[l][i2], a1 = hs[l+8][i2];
    float v00 = bf2f(a0&0xffff), v01 = bf2f(a0>>16);
    float v10 = bf2f(a1&0xffff), v11 = bf2f(a1>>16);
    const int i = 2*i2;
    #pragma unroll
    for (int r=0;r<8;r++){
      acc[r] = fmaf(w3[(r*128+i)*2],     v00, acc[r]);
      acc[r] = fmaf(w3[(r*128+i)*2+1],   v10, acc[r]);
      acc[r] = fmaf(w3[(r*128+i+1)*2],   v01, acc[r]);
      acc[r] = fmaf(w3[(r*128+i+1)*2+1], v11, acc[r]);
    }
  }
  float m = -1e30f;
  #pragma unroll
  for (int r=0;r<8;r++){ acc[r] = rrelu(acc[r]); m = fmaxf(m, acc[r]); }
  float s = 0.f;
  #pragma unroll
  for (int r=0;r<8;r++) s += __expf(acc[r]-m);
  const float lse = m + __logf(s);
  const int t = t0 + l;
  const float* ub = u + ((size_t)b*4096 + t)*8;
  float y[8], m2 = -1e30f;
  #pragma unroll
  for (int r=0;r<8;r++){
    float g = -__logf(-__logf(ub[r]));
    y[r] = (acc[r] - lse + g)*10.f;
    m2 = fmaxf(m2, y[r]);
  }
  float s2 = 0.f;
  #pragma unroll
  for (int r=0;r<8;r++){ y[r] = __expf(y[r]-m2); s2 += y[r]; }
  const float inv = 1.f/s2;
  #pragma unroll
  for (int r=0;r<8;r++){
    y[r] *= inv;
    genz[((size_t)b*8+r)*4096 + t] = y[r];
  }
  ui4 zp = { (unsigned)f2bf(y[0]) | ((unsigned)f2bf(y[1])<<16),
             (unsigned)f2bf(y[2]) | ((unsigned)f2bf(y[3])<<16),
             (unsigned)f2bf(y[4]) | ((unsigned)f2bf(y[5])<<16),
             (unsigned)f2bf(y[6]) | ((unsigned)f2bf(y[7])<<16) };
  ui4 zz = {0,0,0,0};
  ui4* zd = (ui4*)(zt + ((size_t)b*4096 + t)*32);
  zd[0]=zp; zd[1]=zz; zd[2]=zz; zd[3]=zz;
}

// ---- MoE layer 0, LDS-staged dbuf weights, coalesced NT output ----
// 8 waves = 2(o) x 4(t); block tile o64 x t256; wave o32(m2) x t64(n4).
__global__ __launch_bounds__(512) void moe1_m(
  const unsigned short* __restrict__ h2t,  // [8][N2][128]
  const float* __restrict__ genz,
  const unsigned short* __restrict__ zt,   // [8][4096][32]
  const unsigned short* __restrict__ pw0b, // [8][256][128]
  const unsigned short* __restrict__ pb0e, // [256][32]
  unsigned short* __restrict__ hidt)       // [8][4096][256]
{
  __shared__ __align__(16) char smem[16384*2 + 8192];
  char* abuf0 = smem;
  char* abuf1 = smem + 16384;
  float* zl = (float*)(smem + 32768);      // [8][256]

  const int b = blockIdx.z, tb = blockIdx.y*256, ob = blockIdx.x*64;
  const int tid = threadIdx.x;
  for (int e = tid; e < 2048; e += 512)
    zl[e] = genz[((size_t)b*8 + (e>>8))*4096 + tb + (e&255)];

  const int wid = tid>>6, l = tid&63, lo = l&15, hi = l>>4;
  const int wo = wid&1, wt = wid>>1;

  // B fragments (held whole kernel) + bias accumulator via K=32 MFMA on z
  bf16x8 bfr[4][4], zfr[4];
  #pragma unroll
  for (int n=0;n<4;n++){
    int t = tb + wt*64 + n*16 + lo;
    #pragma unroll
    for (int kk=0;kk<4;kk++)
      bfr[n][kk] = *(const bf16x8*)(h2t + ((size_t)b*N2 + t + 8)*128 + kk*32 + hi*8);
    zfr[n] = *(const bf16x8*)(zt + ((size_t)b*4096 + t)*32 + hi*8);
  }
  f32x4 acc[2][4];
  #pragma unroll
  for (int m=0;m<2;m++){
    bf16x8 pf = *(const bf16x8*)(pb0e + (size_t)(ob + wo*32 + m*16 + lo)*32 + hi*8);
    #pragma unroll
    for (int n=0;n<4;n++)
      acc[m][n] = __builtin_amdgcn_mfma_f32_16x16x32_bf16(pf, zfr[n], (f32x4){0.f,0.f,0.f,0.f}, 0,0,0);
  }

  // prologue: stage r=0 panel (o64 x K128 = 16KB)
  {
    const char* src = (const char*)(pw0b + (size_t)ob*128);
    #pragma unroll
    for (int i=0;i<2;i++){
      int c = tid + i*512, row = c>>4, cc = c&15;
      ui4 v = *(const ui4*)(src + row*256 + cc*16);
      *(ui4*)(abuf0 + row*256 + ((cc*16) ^ ((row&7)<<4))) = v;
    }
  }
  __syncthreads();

  #pragma unroll
  for (int r=0;r<8;r++){
    char* cur = (r&1) ? abuf1 : abuf0;
    char* nxt = (r&1) ? abuf0 : abuf1;
    ui4 stg[2];
    if (r < 7){
      const char* src = (const char*)(pw0b + ((size_t)(r+1)*256 + ob)*128);
      #pragma unroll
      for (int i=0;i<2;i++){
        int c = tid + i*512;
        stg[i] = *(const ui4*)(src + (c>>4)*256 + (c&15)*16);
      }
    }
    f32x4 ar[2][4];
    #pragma unroll
    for (int m=0;m<2;m++)
      #pragma unroll
      for (int n=0;n<4;n++) ar[m][n] = (f32x4){0.f,0.f,0.f,0.f};
    #pragma unroll
    for (int kk=0;kk<4;kk++){
      #pragma unroll
      for (int m=0;m<2;m++){
        int row = wo*32 + m*16 + lo;
        int kb  = kk*64 + hi*16;
        bf16x8 af = *(const bf16x8*)(cur + row*256 + (kb ^ ((row&7)<<4)));
        #pragma unroll
        for (int n=0;n<4;n++)
          ar[m][n] = __builtin_amdgcn_mfma_f32_16x16x32_bf16(af, bfr[n][kk], ar[m][n], 0,0,0);
      }
    }
    #pragma unroll
    for (int n=0;n<4;n++){
      float zv = zl[r*256 + wt*64 + n*16 + lo];
      #pragma unroll
      for (int m=0;m<2;m++)
        #pragma unroll
        for (int c2=0;c2<4;c2++)
          acc[m][n][c2] = fmaf(zv, ar[m][n][c2], acc[m][n][c2]);
    }
    if (r < 7){
      #pragma unroll
      for (int i=0;i<2;i++){
        int c = tid + i*512;
        *(ui4*)(nxt + (c>>4)*256 + (((c&15)*16) ^ (((c>>4)&7)<<4))) = stg[i];
      }
    }
    __syncthreads();
  }

  // stage [t256][o64] tile in LDS (32KB, reuses abuf0+abuf1), then NT-coalesced out
  char* outs = smem;
  #pragma unroll
  for (int m=0;m<2;m++){
    int ol2 = (wo*32 + m*16 + hi*4)*2;
    #pragma unroll
    for (int n=0;n<4;n++){
      int tl = wt*64 + n*16 + lo;
      us4 v;
      v.x=f2bf(acc[m][n][0]); v.y=f2bf(acc[m][n][1]);
      v.z=f2bf(acc[m][n][2]); v.w=f2bf(acc[m][n][3]);
      *(us4*)(outs + tl*128 + (ol2 ^ ((tl&7)<<4))) = v;
    }
  }
  __syncthreads();
  #pragma unroll
  for (int i=0;i<4;i++){
    int c = tid + i*512;
    int row = c>>3, cc = c&7;
    ui4 v = *(const ui4*)(outs + row*128 + ((cc*16) ^ ((row&7)<<4)));
    st_nt(hidt + ((size_t)b*4096 + tb + row)*256 + ob + cc*8, v);
  }
}

// ---- MoE layer 1, LDS-staged dbuf weights, full K=256 per wave ----
// 8 waves = 8(t); block tile o64 x t256; wave o64(m4) x t32(n2).
__global__ __launch_bounds__(512) void moe2_m(
  const unsigned short* __restrict__ hidt, // [8][4096][256]
  const float* __restrict__ genz,
  const unsigned short* __restrict__ zt,
  const unsigned short* __restrict__ pw1b, // [8][64][256]
  const unsigned short* __restrict__ pb1e, // [64][32]
  float* __restrict__ out)
{
  __shared__ __align__(16) char smem[32768*2 + 8192];
  char* abuf0 = smem;
  char* abuf1 = smem + 32768;
  float* zl  = (float*)(smem + 65536);     // [8][256]

  const int b = blockIdx.y, tb = blockIdx.x*256;
  const int tid = threadIdx.x;
  for (int e = tid; e < 2048; e += 512)
    zl[e] = genz[((size_t)b*8 + (e>>8))*4096 + tb + (e&255)];

  const int wid = tid>>6, l = tid&63, lo = l&15, hi = l>>4;

  bf16x8 bfr[2][8];
  #pragma unroll
  for (int n=0;n<2;n++){
    int t = tb + wid*32 + n*16 + lo;
    #pragma unroll
    for (int kk=0;kk<8;kk++)
      bfr[n][kk] = ld_nt((const bf16x8*)(hidt + ((size_t)b*4096 + t)*256 + kk*32 + hi*8));
  }
  f32x4 acc[4][2];
  #pragma unroll
  for (int m=0;m<4;m++){
    bf16x8 pf = *(const bf16x8*)(pb1e + (size_t)(m*16 + lo)*32 + hi*8);
    #pragma unroll
    for (int n=0;n<2;n++){
      bf16x8 zf = *(const bf16x8*)(zt + ((size_t)b*4096 + tb + wid*32 + n*16 + lo)*32 + hi*8);
      acc[m][n] = __builtin_amdgcn_mfma_f32_16x16x32_bf16(pf, zf, (f32x4){0.f,0.f,0.f,0.f}, 0,0,0);
    }
  }

  {
    const char* src = (const char*)pw1b;
    #pragma unroll
    for (int i=0;i<4;i++){
      int c = tid + i*512, row = c>>5, cc = c&31;
      ui4 v = *(const ui4*)(src + row*512 + cc*16);
      *(ui4*)(abuf0 + row*512 + ((cc*16) ^ ((row&7)<<4))) = v;
    }
  }
  __syncthreads();

  #pragma unroll
  for (int r=0;r<8;r++){
    char* cur = (r&1) ? abuf1 : abuf0;
    char* nxt = (r&1) ? abuf0 : abuf1;
    ui4 stg[4];
    if (r < 7){
      const char* src = (const char*)(pw1b + (size_t)(r+1)*16384);
      #pragma unroll
      for (int i=0;i<4;i++){
        int c = tid + i*512;
        stg[i] = *(const ui4*)(src + (c>>5)*512 + (c&31)*16);
      }
    }
    f32x4 ar[4][2];
    #pragma unroll
    for (int m=0;m<4;m++)
      #pragma unroll
      for (int n=0;n<2;n++) ar[m][n] = (f32x4){0.f,0.f,0.f,0.f};
    #pragma unroll
    for (int kk=0;kk<8;kk++){
      #pragma unroll
      for (int m=0;m<4;m++){
        int row = m*16 + lo;
        int kb  = kk*64 + hi*16;
        bf16x8 af = *(const bf16x8*)(cur + row*512 + (kb ^ ((row&7)<<4)));
        #pragma unroll
        for (int n=0;n<2;n++)
          ar[m][n] = __builtin_amdgcn_mfma_f32_16x16x32_bf16(af, bfr[n][kk], ar[m][n], 0,0,0);
      }
    }
    #pragma unroll
    for (int n=0;n<2;n++){
      float zv = zl[r*256 + wid*32 + n*16 + lo];
      #pragma unroll
      for (int m=0;m<4;m++)
        #pragma unroll
        for (int c2=0;c2<4;c2++)
          acc[m][n][c2] = fmaf(zv, ar[m][n][c2], acc[m][n][c2]);
    }
    if (r < 7){
      #pragma unroll
      for (int i=0;i<4;i++){
        int c = tid + i*512;
        *(ui4*)(nxt + (c>>5)*512 + (((c&31)*16) ^ (((c>>5)&7)<<4))) = stg[i];
      }
    }
    __syncthreads();
  }

  #pragma unroll
  for (int m=0;m<4;m++){
    #pragma unroll
    for (int n=0;n<2;n++){
      int t = tb + wid*32 + n*16 + lo;
      #pragma unroll
      for (int c2=0;c2<4;c2++){
        int o = m*16 + hi*4 + c2;
        float v = acc[m][n][c2];
        if (o < 32)
          out[((size_t)b*32 + o)*4096 + t] = v;
        else {
          float e = __expf(2.f*v);
          float th = 1.f - 2.f/(e+1.f);
          out[(size_t)1048576 + ((size_t)b*32 + (o-32))*4096 + t] = 0.5f + 0.5f*th + 0.001f;
        }
      }
    }
  }
}

extern "C" void kernel_launch(void* const* d_in, const int* in_sizes, int n_in,
                              void* d_out, int out_size, void* d_ws, size_t ws_size,
                              hipStream_t stream) {
  const float* x   = (const float*)d_in[0];
  const float* u   = (const float*)d_in[1];
  const float* w0  = (const float*)d_in[2];
  const float* b0  = (const float*)d_in[3];
  const float* w1  = (const float*)d_in[4];
  const float* b1  = (const float*)d_in[5];
  const float* w2  = (const float*)d_in[6];
  const float* b2  = (const float*)d_in[7];
  const float* w3  = (const float*)d_in[8];
  const float* b3  = (const float*)d_in[9];
  const float* pw0 = (const float*)d_in[10];
  const float* pb0 = (const float*)d_in[11];
  const float* pw1 = (const float*)d_in[12];
  const float* pb1 = (const float*)d_in[13];

  float* out  = (float*)d_out;
  float* genz = out + (size_t)2*8*32*4096;

  char* p = (char*)d_ws;
  unsigned short* xt   = (unsigned short*)p; p += 2104832;   // 8*4111*32
  unsigned short* h0t  = (unsigned short*)p; p += 8417280;   // 8*4110*128
  unsigned short* h1t  = (unsigned short*)p; p += 8413184;   // 8*4108*128
  unsigned short* h2t  = (unsigned short*)p; p += 8404992;   // 8*4104*128
  unsigned short* ztb  = (unsigned short*)p; p += 2097152;   // 8*4096*32
  unsigned short* hidt = (unsigned short*)p; p += 16777216;  // 8*4096*256
  unsigned short* w0e  = (unsigned short*)p; p += 16384;
  unsigned short* w1e  = (unsigned short*)p; p += 65536;
  unsigned short* w2e  = (unsigned short*)p; p += 65536;
  unsigned short* pw0b = (unsigned short*)p; p += 524288;
  unsigned short* pw1b = (unsigned short*)p; p += 262144;
  unsigned short* pb0e = (unsigned short*)p; p += 16384;
  unsigned short* pb1e = (unsigned short*)p; p += 4096;

  prep_w<<<1864, 256, 0, stream>>>(w0,w1,w2,pw0,pw1,pb0,pb1,
                                   w0e,w1e,w2e,pw0b,pw1b,pb0e,pb1e);
  prep_xt<<<dim3(65,8), 64, 0, stream>>>(x, xt);
  conv_g<32,1,NX,N0><<<dim3(65,8), 256, 0, stream>>>(xt,  w0e, b0, h0t);
  conv_g<128,2,N0,N1><<<dim3(65,8), 256, 0, stream>>>(h0t, w1e, b1, h1t);
  conv_g<128,4,N1,N2><<<dim3(65,8), 256, 0, stream>>>(h1t, w2e, b2, h2t);
  gumbel_g<<<dim3(16,8), 256, 0, stream>>>(h2t, w3, b3, u, genz, ztb);
  moe1_m<<<dim3(4,16,8), 512, 0, stream>>>(h2t, genz, ztb, pw0b, pb0e, hidt);
  moe2_m<<<dim3(16,8), 512, 0, stream>>>(hidt, genz, ztb, pw1b, pb1e, out);
}